// Round 1
// baseline (2588.510 us; speedup 1.0000x reference)
//
#include <hip/hip_runtime.h>
#include <math.h>

#define N 4096
#define D 128
#define P 16
#define NT (N / 64)

#define BM 64
#define BN 64
#define BK 32
#define PAD 4  // row stride 68 floats = 272B, 16B-aligned for float4 LDS reads

// ---------------------------------------------------------------------------
// K1: rnorm[p*N+n] = 1 / max(||C[n,:]*w[p,:]||_2, 1e-12), computed in f64.
// ---------------------------------------------------------------------------
__global__ void k_norms(const float* __restrict__ c, const float* __restrict__ w,
                        double* __restrict__ rnorm) {
    int t = blockIdx.x * blockDim.x + threadIdx.x;
    if (t >= P * N) return;
    int p = t / N;
    int n = t - p * N;
    const float* cr = c + (size_t)n * D;
    const float* wr = w + p * D;
    double s = 0.0;
#pragma unroll 8
    for (int d = 0; d < D; ++d) {
        double v = (double)cr[d] * (double)wr[d];
        s += v * v;
    }
    double nrm = sqrt(s);
    if (nrm < 1e-12) nrm = 1e-12;
    rnorm[t] = 1.0 / nrm;
}

// ---------------------------------------------------------------------------
// K2: attention (pre-mask) = Z Z^T / 16, Z[n, p*128+d] = c[n,d]*w[p,d]*rnorm[p,n].
// f32 register-tiled GEMM; upper-triangular blocks only (ti <= tj), mirrored.
// Writes RAW (pre-mask) values; K3 applies the mask.
// ---------------------------------------------------------------------------
__global__ __launch_bounds__(256) void k_gemm(const float* __restrict__ c,
                                              const float* __restrict__ w,
                                              const double* __restrict__ rnorm,
                                              float* __restrict__ out) {
    int tj = blockIdx.x, ti = blockIdx.y;
    if (ti > tj) return;

    __shared__ __align__(16) float As[BK][BM + PAD];
    __shared__ __align__(16) float Bs[BK][BN + PAD];

    int tid = threadIdx.x;
    int tx = tid & 15;       // 16 columns of threads
    int ty = tid >> 4;       // 16 rows of threads
    int n0 = ti * BM, m0 = tj * BN;

    float acc[4][4] = {};

    for (int k0 = 0; k0 < P * D; k0 += BK) {
        // stage A-tile: e -> (nl = e/BK, kl = e%BK); consecutive lanes read
        // consecutive d of the same context row -> coalesced.
        for (int e = tid; e < BM * BK; e += 256) {
            int nl = e >> 5;          // /BK
            int kl = e & 31;          // %BK
            int k = k0 + kl;
            int p = k >> 7, d = k & 127;
            int n = n0 + nl;
            float z = c[(size_t)n * D + d] * w[p * D + d] * (float)rnorm[p * N + n];
            As[kl][nl] = z;
        }
        for (int e = tid; e < BN * BK; e += 256) {
            int ml = e >> 5;
            int kl = e & 31;
            int k = k0 + kl;
            int p = k >> 7, d = k & 127;
            int m = m0 + ml;
            float z = c[(size_t)m * D + d] * w[p * D + d] * (float)rnorm[p * N + m];
            Bs[kl][ml] = z;
        }
        __syncthreads();

#pragma unroll
        for (int kk = 0; kk < BK; ++kk) {
            float4 a4 = *reinterpret_cast<const float4*>(&As[kk][ty * 4]);
            float4 b4 = *reinterpret_cast<const float4*>(&Bs[kk][tx * 4]);
            float ar[4] = {a4.x, a4.y, a4.z, a4.w};
            float br[4] = {b4.x, b4.y, b4.z, b4.w};
#pragma unroll
            for (int i = 0; i < 4; ++i)
#pragma unroll
                for (int j = 0; j < 4; ++j) acc[i][j] += ar[i] * br[j];
        }
        __syncthreads();
    }

    // write raw (pre-mask) mean; mirror for off-diagonal tiles
#pragma unroll
    for (int i = 0; i < 4; ++i) {
        int n = n0 + ty * 4 + i;
#pragma unroll
        for (int j = 0; j < 4; ++j) {
            int m = m0 + tx * 4 + j;
            float a = acc[i][j] * (1.0f / 16.0f);
            out[(size_t)n * N + m] = a;
            if (ti != tj) out[(size_t)m * N + n] = a;
        }
    }
}

// ---------------------------------------------------------------------------
// K3: mask epilogue. Entries far from 0.1 masked directly; entries within
// 2e-3 of the threshold recomputed exactly in f64 (matches f64 numpy gold).
// ---------------------------------------------------------------------------
__global__ __launch_bounds__(256) void k_fix(const float* __restrict__ c,
                                             const float* __restrict__ w,
                                             const double* __restrict__ rnorm,
                                             float* __restrict__ out) {
    __shared__ double w2[D][P];  // w2[d][p] = (double)w[p,d]^2   (16 KB)
    for (int e = threadIdx.x; e < P * D; e += blockDim.x) {
        int p = e >> 7, d = e & 127;
        double wv = (double)w[p * D + d];
        w2[d][p] = wv * wv;
    }
    __syncthreads();

    size_t idx = (size_t)blockIdx.x * blockDim.x + threadIdx.x;
    if (idx >= (size_t)N * N) return;

    float a = out[idx];
    if (fabsf(a - 0.1f) >= 2e-3f) {
        out[idx] = (a > 0.1f) ? a : 0.0f;
        return;
    }

    // exact f64 recompute of this entry
    int n = (int)(idx >> 12);  // /4096
    int m = (int)(idx & 4095);
    const float* cn = c + (size_t)n * D;
    const float* cm = c + (size_t)m * D;
    double accp[P] = {0};
    for (int d = 0; d < D; ++d) {
        double prod = (double)cn[d] * (double)cm[d];
#pragma unroll
        for (int p = 0; p < P; ++p) accp[p] += prod * w2[d][p];
    }
    double s = 0.0;
#pragma unroll
    for (int p = 0; p < P; ++p)
        s += accp[p] * rnorm[p * N + n] * rnorm[p * N + m];
    s *= (1.0 / 16.0);
    out[idx] = (s > 0.1) ? (float)s : 0.0f;
}

// ---------------------------------------------------------------------------
extern "C" void kernel_launch(void* const* d_in, const int* in_sizes, int n_in,
                              void* d_out, int out_size, void* d_ws, size_t ws_size,
                              hipStream_t stream) {
    const float* c = (const float*)d_in[0];   // [N, D]
    const float* w = (const float*)d_in[1];   // [P, D]
    float* out = (float*)d_out;               // [N, N]
    double* rnorm = (double*)d_ws;            // P*N doubles = 512 KB

    k_norms<<<(P * N + 255) / 256, 256, 0, stream>>>(c, w, rnorm);

    dim3 g2(NT, NT);
    k_gemm<<<g2, 256, 0, stream>>>(c, w, rnorm, out);

    k_fix<<<(size_t)N * N / 256, 256, 0, stream>>>(c, w, rnorm, out);
}

// Round 2
// 494.953 us; speedup vs baseline: 5.2298x; 5.2298x over previous
//
#include <hip/hip_runtime.h>
#include <math.h>

#define N 4096
#define D 128
#define P 16
#define K2 2048          // P*D
#define NT 32            // 128-wide tiles per dim
#define NBLK (NT * (NT + 1) / 2)   // 528 upper-tri blocks
#define WIN 5e-3f        // mask-recompute window (> 4.2e-3 analytic bf16 bound)

typedef __attribute__((ext_vector_type(8))) __bf16 bf16x8;
typedef __attribute__((ext_vector_type(4))) float f32x4;
typedef __attribute__((ext_vector_type(8))) unsigned short ushort8;
typedef __attribute__((address_space(1))) const unsigned int* gptr_t;
typedef __attribute__((address_space(3))) unsigned int* lptr_t;

__device__ inline unsigned short f2bf(float f) {
    unsigned int u = __float_as_uint(f);
    unsigned int r = (u + 0x7FFFu + ((u >> 16) & 1u)) >> 16;
    return (unsigned short)r;
}

// ---------------------------------------------------------------------------
// K1: rnorm[p*N+n] = 1 / max(||C[n,:]*w[p,:]||, 1e-12) in f64.
// ---------------------------------------------------------------------------
__global__ void k_norms(const float* __restrict__ c, const float* __restrict__ w,
                        double* __restrict__ rnorm) {
    int t = blockIdx.x * blockDim.x + threadIdx.x;
    if (t >= P * N) return;
    int p = t / N;
    int n = t - p * N;
    const float* cr = c + (size_t)n * D;
    const float* wr = w + p * D;
    double s = 0.0;
#pragma unroll 8
    for (int d = 0; d < D; ++d) {
        double v = (double)cr[d] * (double)wr[d];
        s += v * v;
    }
    double nrm = sqrt(s);
    if (nrm < 1e-12) nrm = 1e-12;
    rnorm[t] = 1.0 / nrm;
}

// ---------------------------------------------------------------------------
// K2: pack Z[n][k] = c[n,d]*w[p,d]*rnorm[p,n] to bf16 (RNE). One block per row.
// thread t: p = t>>4, d0 = (t&15)*8, writes 8 consecutive bf16 (16B store).
// ---------------------------------------------------------------------------
__global__ __launch_bounds__(256) void k_prep(const float* __restrict__ c,
                                              const float* __restrict__ w,
                                              const double* __restrict__ rnorm,
                                              unsigned short* __restrict__ zb) {
    int n = blockIdx.x;
    int tid = threadIdx.x;
    int p = tid >> 4;
    int d0 = (tid & 15) * 8;
    float rn = (float)rnorm[p * N + n];
    const float* cc = c + (size_t)n * D + d0;
    const float* ww = w + p * D + d0;
    ushort8 o;
#pragma unroll
    for (int i = 0; i < 8; ++i) o[i] = f2bf(cc[i] * ww[i] * rn);
    *(ushort8*)&zb[(size_t)n * K2 + tid * 8] = o;
}

// ---------------------------------------------------------------------------
// K3: bf16 MFMA GEMM  out = Z Z^T / 16 (raw, pre-mask).
// 128x128 tile, BK=32, 4 waves (2x2 of 64x64), m97 structure with
// global_load_lds width 16. Upper-triangular blocks only; mirror via LDS
// transpose with coalesced float4 stores.
// ---------------------------------------------------------------------------
__global__ __launch_bounds__(256, 2) void k_gemm(const unsigned short* __restrict__ zb,
                                                 float* __restrict__ out) {
    __shared__ __align__(16) union {
        struct { unsigned short A[128 * 32]; unsigned short B[128 * 32]; } st;
        float T[4 * 64 * 68];   // per-wave 64x64 transpose buf, stride 68 (16B-aligned rows)
    } sm;

    int tid = threadIdx.x;
    int lane = tid & 63, wv = tid >> 6;
    int wr = wv >> 1, wc = wv & 1;

    // triangular decode: block -> (ti, tj), ti <= tj
    int b = blockIdx.x, ti = 0;
    while (b >= NT - ti) { b -= NT - ti; ++ti; }
    int tj = ti + b;
    int n0 = ti * 128, m0 = tj * 128;

    f32x4 acc[4][4] = {};

    int lrow = lane >> 2;            // 0..15 within a 16-row slice
    int lchunk = (lane & 3) * 8;     // k-offset of this lane's 16B

    for (int k0 = 0; k0 < K2; k0 += 32) {
        // stage A,B tiles: 8 slices of 16 rows each; wave wv owns slices wv and wv+4
#pragma unroll
        for (int h = 0; h < 2; ++h) {
            int s = h * 4 + wv;
            int row = s * 16 + lrow;
            const void* ga = (const void*)(zb + (size_t)(n0 + row) * K2 + k0 + lchunk);
            __builtin_amdgcn_global_load_lds((gptr_t)ga, (lptr_t)(sm.st.A + s * 512), 16, 0, 0);
            const void* gb = (const void*)(zb + (size_t)(m0 + row) * K2 + k0 + lchunk);
            __builtin_amdgcn_global_load_lds((gptr_t)gb, (lptr_t)(sm.st.B + s * 512), 16, 0, 0);
        }
        __syncthreads();

        bf16x8 af[4], bfr[4];
        int kk = (lane >> 4) * 8;
        int rsel = lane & 15;
#pragma unroll
        for (int f = 0; f < 4; ++f) {
            af[f]  = *(bf16x8*)&sm.st.A[(wr * 64 + f * 16 + rsel) * 32 + kk];
            bfr[f] = *(bf16x8*)&sm.st.B[(wc * 64 + f * 16 + rsel) * 32 + kk];
        }
#pragma unroll
        for (int i = 0; i < 4; ++i)
#pragma unroll
            for (int j = 0; j < 4; ++j)
                acc[i][j] = __builtin_amdgcn_mfma_f32_16x16x32_bf16(af[i], bfr[j], acc[i][j], 0, 0, 0);
        __syncthreads();
    }

    // direct store (upper block region), scaled by 1/16
    int colD = lane & 15, rq = lane >> 4;
#pragma unroll
    for (int i = 0; i < 4; ++i)
#pragma unroll
        for (int j = 0; j < 4; ++j) {
            int rbase = n0 + wr * 64 + i * 16 + rq * 4;
            int ccol = m0 + wc * 64 + j * 16 + colD;
#pragma unroll
            for (int q = 0; q < 4; ++q)
                out[(size_t)(rbase + q) * N + ccol] = acc[i][j][q] * 0.0625f;
        }

    if (ti == tj) return;

    // mirror: transpose wave's 64x64 in LDS, then coalesced float4 stores
    __syncthreads();   // st.* dead -> reuse as T
    float* Tw = sm.T + wv * (64 * 68);
#pragma unroll
    for (int i = 0; i < 4; ++i)
#pragma unroll
        for (int j = 0; j < 4; ++j) {
            int rl = i * 16 + rq * 4;
            int cl = j * 16 + colD;
#pragma unroll
            for (int q = 0; q < 4; ++q)
                Tw[cl * 68 + rl + q] = acc[i][j][q] * 0.0625f;
        }
    __syncthreads();
#pragma unroll
    for (int it = 0; it < 16; ++it) {
        int rr = it * 4 + rq;        // local col of wave tile = mirror row
        int cc = colD * 4;           // local row of wave tile = mirror col
        float4 v = *(float4*)&Tw[rr * 68 + cc];
        size_t o = (size_t)(m0 + wc * 64 + rr) * N + n0 + wr * 64 + cc;
        *(float4*)&out[o] = v;
    }
}

// ---------------------------------------------------------------------------
// K4: mask epilogue. |a-0.1| >= WIN -> mask directly (bf16 error bound 4.2e-3
// guarantees correct side). Else: wave-cooperative exact f64 recompute
// (2 d's per lane, shuffle reduce), mask in f64 -> matches np/f64 gold.
// ---------------------------------------------------------------------------
__global__ __launch_bounds__(256) void k_fix(const float* __restrict__ c,
                                             const float* __restrict__ w,
                                             const double* __restrict__ rnorm,
                                             float* __restrict__ out) {
    __shared__ double w2[D][17];
    for (int e = threadIdx.x; e < P * D; e += 256) {
        int p = e >> 7, d = e & 127;
        double wv = (double)w[p * D + d];
        w2[d][p] = wv * wv;
    }
    __syncthreads();

    int tid = threadIdx.x;
    int lane = tid & 63;
    int wvb = tid & ~63;
    size_t base4 = (size_t)blockIdx.x * 256 + tid;
    float4 v = *(float4*)&out[base4 * 4];
    float vv[4] = {v.x, v.y, v.z, v.w};
    bool resolved[4] = {false, false, false, false};

#pragma unroll
    for (int j = 0; j < 4; ++j) {
        bool flag = fabsf(vv[j] - 0.1f) < WIN;
        unsigned long long mb = __ballot(flag);
        while (mb) {
            int src = __ffsll((unsigned long long)mb) - 1;
            mb &= mb - 1;
            size_t idx = ((size_t)blockIdx.x * 256 + wvb + src) * 4 + j;
            int n = (int)(idx >> 12), m = (int)(idx & (N - 1));
            int d0 = lane, d1 = lane + 64;
            double pr0 = (double)c[n * D + d0] * (double)c[m * D + d0];
            double pr1 = (double)c[n * D + d1] * (double)c[m * D + d1];
            double t = 0.0;
#pragma unroll
            for (int p = 0; p < P; ++p) {
                double s = pr0 * w2[d0][p] + pr1 * w2[d1][p];
                t += s * (rnorm[p * N + n] * rnorm[p * N + m]);
            }
#pragma unroll
            for (int o = 32; o; o >>= 1) t += __shfl_xor(t, o, 64);
            if (lane == src) {
                double fin = t * 0.0625;
                vv[j] = (fin > 0.1) ? (float)fin : 0.0f;
                resolved[j] = true;
            }
        }
        if (!resolved[j]) vv[j] = (vv[j] > 0.1f) ? vv[j] : 0.0f;
    }
    *(float4*)&out[base4 * 4] = make_float4(vv[0], vv[1], vv[2], vv[3]);
}

// ---------------------------------------------------------------------------
extern "C" void kernel_launch(void* const* d_in, const int* in_sizes, int n_in,
                              void* d_out, int out_size, void* d_ws, size_t ws_size,
                              hipStream_t stream) {
    const float* c = (const float*)d_in[0];   // [N, D]
    const float* w = (const float*)d_in[1];   // [P, D]
    float* out = (float*)d_out;               // [N, N]
    double* rnorm = (double*)d_ws;                               // 512 KB
    unsigned short* zb = (unsigned short*)((char*)d_ws + (size_t)P * N * 8);  // 16 MB

    k_norms<<<(P * N + 255) / 256, 256, 0, stream>>>(c, w, rnorm);
    k_prep<<<N, 256, 0, stream>>>(c, w, rnorm, zb);
    k_gemm<<<NBLK, 256, 0, stream>>>(zb, out);
    k_fix<<<(size_t)N * N / 1024, 256, 0, stream>>>(c, w, rnorm, out);
}

// Round 3
// 249.732 us; speedup vs baseline: 10.3652x; 1.9819x over previous
//
#include <hip/hip_runtime.h>
#include <math.h>

#define N 4096
#define D 128
#define P 16
#define NT 32
#define NBLK (NT * (NT + 1) / 2)   // 528 upper-tri blocks
#define LCAP 2048                  // per-block LDS worklist capacity
#define CAP (1u << 20)             // global worklist capacity (4 MB)
#define WIN_HI 7e-4f               // hi/lo-split mask window (> 4.9e-4 worst-case bound)
#define WIN_LO 5e-3f               // single-bf16 window (fallback path)

typedef __attribute__((ext_vector_type(8))) __bf16 bf16x8;
typedef __attribute__((ext_vector_type(4))) float f32x4;
typedef __attribute__((ext_vector_type(8))) unsigned short ushort8;
typedef __attribute__((address_space(1))) const unsigned int* gptr_t;
typedef __attribute__((address_space(3))) unsigned int* lptr_t;

__device__ inline unsigned short f2bf(float f) {
    unsigned int u = __float_as_uint(f);
    return (unsigned short)((u + 0x7FFFu + ((u >> 16) & 1u)) >> 16);
}

// ---------------------------------------------------------------------------
// K1: rnorm[p*N+n] = 1 / max(||C[n,:]*w[p,:]||, 1e-12) in f64.
// ---------------------------------------------------------------------------
__global__ void k_norms(const float* __restrict__ c, const float* __restrict__ w,
                        double* __restrict__ rnorm) {
    int t = blockIdx.x * blockDim.x + threadIdx.x;
    if (t >= P * N) return;
    int p = t / N;
    int n = t - p * N;
    const float* cr = c + (size_t)n * D;
    const float* wr = w + p * D;
    double s = 0.0;
#pragma unroll 8
    for (int d = 0; d < D; ++d) {
        double v = (double)cr[d] * (double)wr[d];
        s += v * v;
    }
    double nrm = sqrt(s);
    if (nrm < 1e-12) nrm = 1e-12;
    rnorm[t] = 1.0 / nrm;
}

__global__ void k_init(unsigned* gcnt, unsigned* govf) { *gcnt = 0; *govf = 0; }

// ---------------------------------------------------------------------------
// K2a: pack Z hi/lo:  z2[n][k] = bf16_hi, z2[n][2048+k] = bf16_lo (Dekker split)
// ---------------------------------------------------------------------------
__global__ __launch_bounds__(256) void k_prep2(const float* __restrict__ c,
                                               const float* __restrict__ w,
                                               const double* __restrict__ rnorm,
                                               unsigned short* __restrict__ z2) {
    int n = blockIdx.x;
    int tid = threadIdx.x;
    int p = tid >> 4;
    int d0 = (tid & 15) * 8;
    float rn = (float)rnorm[p * N + n];
    const float* cc = c + (size_t)n * D + d0;
    const float* ww = w + p * D + d0;
    ushort8 hi, lo;
#pragma unroll
    for (int i = 0; i < 8; ++i) {
        float z = cc[i] * ww[i] * rn;
        unsigned short h = f2bf(z);
        float hf = __uint_as_float(((unsigned)h) << 16);
        hi[i] = h;
        lo[i] = f2bf(z - hf);
    }
    *(ushort8*)&z2[(size_t)n * 4096 + tid * 8] = hi;
    *(ushort8*)&z2[(size_t)n * 4096 + 2048 + tid * 8] = lo;
}

// K2b: single-bf16 pack (fallback path)
__global__ __launch_bounds__(256) void k_prep1(const float* __restrict__ c,
                                               const float* __restrict__ w,
                                               const double* __restrict__ rnorm,
                                               unsigned short* __restrict__ zb) {
    int n = blockIdx.x;
    int tid = threadIdx.x;
    int p = tid >> 4;
    int d0 = (tid & 15) * 8;
    float rn = (float)rnorm[p * N + n];
    const float* cc = c + (size_t)n * D + d0;
    const float* ww = w + p * D + d0;
    ushort8 o;
#pragma unroll
    for (int i = 0; i < 8; ++i) o[i] = f2bf(cc[i] * ww[i] * rn);
    *(ushort8*)&zb[(size_t)n * 2048 + tid * 8] = o;
}

// ---------------------------------------------------------------------------
// K3: bf16 MFMA GEMM  out = Z Z^T / 16. 128x128 tile, BK=32, 4 waves.
// FUSED: applies mask in-register, pushes |a-0.1|<WIN_HI entries to worklist
// (raw value stored; k_fix2 overwrites with exact f64 decision).
// ---------------------------------------------------------------------------
template <int KTOT, bool FUSED>
__global__ __launch_bounds__(256, 2) void k_gemm(const unsigned short* __restrict__ zb,
                                                 float* __restrict__ out,
                                                 unsigned* __restrict__ gcnt,
                                                 unsigned* __restrict__ govf,
                                                 unsigned* __restrict__ glist) {
    __shared__ __align__(16) union {
        struct { unsigned short A[128 * 32]; unsigned short B[128 * 32]; } st;
        float T[4 * 64 * 68];
    } sm;
    __shared__ unsigned lds_list[LCAP];
    __shared__ unsigned lds_cnt, lds_base, lds_tot;

    int tid = threadIdx.x;
    if (FUSED && tid == 0) lds_cnt = 0;

    int lane = tid & 63, wv = tid >> 6;
    int wr = wv >> 1, wc = wv & 1;

    int b = blockIdx.x, ti = 0;
    while (b >= NT - ti) { b -= NT - ti; ++ti; }
    int tj = ti + b;
    int n0 = ti * 128, m0 = tj * 128;

    f32x4 acc[4][4] = {};
    int lrow = lane >> 2;
    int lchunk = (lane & 3) * 8;

    for (int k0 = 0; k0 < KTOT; k0 += 32) {
#pragma unroll
        for (int h = 0; h < 2; ++h) {
            int s = h * 4 + wv;
            int row = s * 16 + lrow;
            __builtin_amdgcn_global_load_lds((gptr_t)(zb + (size_t)(n0 + row) * KTOT + k0 + lchunk),
                                             (lptr_t)(sm.st.A + s * 512), 16, 0, 0);
            __builtin_amdgcn_global_load_lds((gptr_t)(zb + (size_t)(m0 + row) * KTOT + k0 + lchunk),
                                             (lptr_t)(sm.st.B + s * 512), 16, 0, 0);
        }
        __syncthreads();

        bf16x8 af[4], bfr[4];
        int kk = (lane >> 4) * 8;
        int rsel = lane & 15;
#pragma unroll
        for (int f = 0; f < 4; ++f) {
            af[f]  = *(bf16x8*)&sm.st.A[(wr * 64 + f * 16 + rsel) * 32 + kk];
            bfr[f] = *(bf16x8*)&sm.st.B[(wc * 64 + f * 16 + rsel) * 32 + kk];
        }
#pragma unroll
        for (int i = 0; i < 4; ++i)
#pragma unroll
            for (int j = 0; j < 4; ++j)
                acc[i][j] = __builtin_amdgcn_mfma_f32_16x16x32_bf16(af[i], bfr[j], acc[i][j], 0, 0, 0);
        __syncthreads();
    }

    int colD = lane & 15, rq = lane >> 4;
    // direct stores (+ flag collection when FUSED)
#pragma unroll
    for (int i = 0; i < 4; ++i)
#pragma unroll
        for (int j = 0; j < 4; ++j) {
            int rbase = n0 + wr * 64 + i * 16 + rq * 4;
            int ccol = m0 + wc * 64 + j * 16 + colD;
#pragma unroll
            for (int q = 0; q < 4; ++q) {
                float a = acc[i][j][q] * 0.0625f;
                float sv;
                if (FUSED) {
                    bool flg = fabsf(a - 0.1f) < WIN_HI;
                    sv = flg ? a : (a > 0.1f ? a : 0.0f);
                    if (flg) {
                        unsigned pos = atomicAdd(&lds_cnt, 1u);
                        unsigned ent = (unsigned)(rbase + q) | ((unsigned)ccol << 12) |
                                       ((ti != tj) ? (1u << 24) : 0u);
                        if (pos < LCAP) lds_list[pos] = ent;
                    }
                } else sv = a;
                out[(size_t)(rbase + q) * N + ccol] = sv;
            }
        }

    if (ti != tj) {
        __syncthreads();  // staging dead -> reuse union as T
        float* Tw = sm.T + wv * (64 * 68);
#pragma unroll
        for (int i = 0; i < 4; ++i)
#pragma unroll
            for (int j = 0; j < 4; ++j) {
                int rl = i * 16 + rq * 4;
                int cl = j * 16 + colD;
#pragma unroll
                for (int q = 0; q < 4; ++q) {
                    float a = acc[i][j][q] * 0.0625f;
                    float sv;
                    if (FUSED) {
                        bool flg = fabsf(a - 0.1f) < WIN_HI;
                        sv = flg ? a : (a > 0.1f ? a : 0.0f);
                    } else sv = a;
                    Tw[cl * 68 + rl + q] = sv;
                }
            }
        __syncthreads();
#pragma unroll
        for (int it = 0; it < 16; ++it) {
            int rr = it * 4 + rq;
            int cc = colD * 4;
            float4 v = *(float4*)&Tw[rr * 68 + cc];
            size_t o = (size_t)(m0 + wc * 64 + rr) * N + n0 + wr * 64 + cc;
            *(float4*)&out[o] = v;
        }
    }

    if (FUSED) {
        __syncthreads();
        if (tid == 0) {
            unsigned tot = lds_cnt;
            unsigned cnt = tot > LCAP ? LCAP : tot;
            lds_tot = cnt;
            lds_base = atomicAdd(gcnt, cnt);
            if (tot > LCAP) atomicOr(govf, 1u);
        }
        __syncthreads();
        unsigned cnt = lds_tot, base = lds_base;
        for (unsigned e = tid; e < cnt; e += 256) {
            unsigned gi = base + e;
            if (gi < CAP) glist[gi] = lds_list[e];
            else atomicOr(govf, 1u);
        }
    }
}

// ---------------------------------------------------------------------------
// K4: exact f64 recompute of worklist entries (64-lane cooperative).
// ---------------------------------------------------------------------------
__global__ __launch_bounds__(256) void k_fix2(const float* __restrict__ c,
                                              const float* __restrict__ w,
                                              const double* __restrict__ rnorm,
                                              const unsigned* __restrict__ gcnt,
                                              const unsigned* __restrict__ glist,
                                              float* __restrict__ out) {
    __shared__ double w2[D][17];
    for (int e = threadIdx.x; e < P * D; e += 256) {
        int p = e >> 7, d = e & 127;
        double wv = (double)w[p * D + d];
        w2[d][p] = wv * wv;
    }
    __syncthreads();

    unsigned count = *gcnt;
    if (count > CAP) count = CAP;
    int lane = threadIdx.x & 63;
    unsigned gw = (blockIdx.x * 256 + threadIdx.x) >> 6;
    unsigned nw = gridDim.x * 4;
    for (unsigned e = gw; e < count; e += nw) {
        unsigned u = glist[e];
        int n = u & 4095, m = (u >> 12) & 4095;
        int d0 = lane, d1 = lane + 64;
        double pr0 = (double)c[n * D + d0] * (double)c[m * D + d0];
        double pr1 = (double)c[n * D + d1] * (double)c[m * D + d1];
        double t = 0.0;
#pragma unroll
        for (int p = 0; p < P; ++p) {
            double s = pr0 * w2[d0][p] + pr1 * w2[d1][p];
            t += s * (rnorm[p * N + n] * rnorm[p * N + m]);
        }
#pragma unroll
        for (int o = 32; o; o >>= 1) t += __shfl_xor(t, o, 64);
        if (lane == 0) {
            double fin = t * 0.0625;
            float res = (fin > 0.1) ? (float)fin : 0.0f;
            out[(size_t)n * N + m] = res;
            if (u >> 24) out[(size_t)m * N + n] = res;
        }
    }
}

// ---------------------------------------------------------------------------
// K5: overflow guard — full-pass resolve, only runs if worklist overflowed.
// ---------------------------------------------------------------------------
__global__ __launch_bounds__(256) void k_guard(const float* __restrict__ c,
                                               const float* __restrict__ w,
                                               const double* __restrict__ rnorm,
                                               const unsigned* __restrict__ govf,
                                               float* __restrict__ out) {
    if (*govf == 0) return;
    __shared__ double w2[D][17];
    for (int e = threadIdx.x; e < P * D; e += 256) {
        int p = e >> 7, d = e & 127;
        double wv = (double)w[p * D + d];
        w2[d][p] = wv * wv;
    }
    __syncthreads();
    int lane = threadIdx.x & 63;
    size_t stride = (size_t)gridDim.x * 256;
    for (size_t idx0 = (size_t)blockIdx.x * 256 + threadIdx.x; idx0 < (size_t)N * N;
         idx0 += stride) {
        float a = out[idx0];
        bool flg = fabsf(a - 0.1f) < WIN_HI;
        unsigned long long mb = __ballot(flg);
        while (mb) {
            int src = __ffsll(mb) - 1;
            mb &= mb - 1;
            size_t idx = idx0 - lane + src;
            int n = (int)(idx >> 12), m = (int)(idx & (N - 1));
            int d0 = lane, d1 = lane + 64;
            double pr0 = (double)c[n * D + d0] * (double)c[m * D + d0];
            double pr1 = (double)c[n * D + d1] * (double)c[m * D + d1];
            double t = 0.0;
#pragma unroll
            for (int p = 0; p < P; ++p) {
                double s = pr0 * w2[d0][p] + pr1 * w2[d1][p];
                t += s * (rnorm[p * N + n] * rnorm[p * N + m]);
            }
#pragma unroll
            for (int o = 32; o; o >>= 1) t += __shfl_xor(t, o, 64);
            if (lane == src) {
                double fin = t * 0.0625;
                out[idx] = (fin > 0.1) ? (float)fin : 0.0f;
            }
        }
        if (!flg) out[idx0] = (a > 0.1f) ? a : 0.0f;
    }
}

// ---------------------------------------------------------------------------
// Fallback full-pass mask fix (round-2 path, used only if ws too small).
// ---------------------------------------------------------------------------
__global__ __launch_bounds__(256) void k_fix_full(const float* __restrict__ c,
                                                  const float* __restrict__ w,
                                                  const double* __restrict__ rnorm,
                                                  float* __restrict__ out) {
    __shared__ double w2[D][17];
    for (int e = threadIdx.x; e < P * D; e += 256) {
        int p = e >> 7, d = e & 127;
        double wv = (double)w[p * D + d];
        w2[d][p] = wv * wv;
    }
    __syncthreads();
    int tid = threadIdx.x;
    int lane = tid & 63;
    int wvb = tid & ~63;
    size_t base4 = (size_t)blockIdx.x * 256 + tid;
    float4 v = *(float4*)&out[base4 * 4];
    float vv[4] = {v.x, v.y, v.z, v.w};
    bool resolved[4] = {false, false, false, false};
#pragma unroll
    for (int j = 0; j < 4; ++j) {
        bool flag = fabsf(vv[j] - 0.1f) < WIN_LO;
        unsigned long long mb = __ballot(flag);
        while (mb) {
            int src = __ffsll(mb) - 1;
            mb &= mb - 1;
            size_t idx = ((size_t)blockIdx.x * 256 + wvb + src) * 4 + j;
            int n = (int)(idx >> 12), m = (int)(idx & (N - 1));
            int d0 = lane, d1 = lane + 64;
            double pr0 = (double)c[n * D + d0] * (double)c[m * D + d0];
            double pr1 = (double)c[n * D + d1] * (double)c[m * D + d1];
            double t = 0.0;
#pragma unroll
            for (int p = 0; p < P; ++p) {
                double s = pr0 * w2[d0][p] + pr1 * w2[d1][p];
                t += s * (rnorm[p * N + n] * rnorm[p * N + m]);
            }
#pragma unroll
            for (int o = 32; o; o >>= 1) t += __shfl_xor(t, o, 64);
            if (lane == src) {
                double fin = t * 0.0625;
                vv[j] = (fin > 0.1) ? (float)fin : 0.0f;
                resolved[j] = true;
            }
        }
        if (!resolved[j]) vv[j] = (vv[j] > 0.1f) ? vv[j] : 0.0f;
    }
    *(float4*)&out[base4 * 4] = make_float4(vv[0], vv[1], vv[2], vv[3]);
}

// ---------------------------------------------------------------------------
extern "C" void kernel_launch(void* const* d_in, const int* in_sizes, int n_in,
                              void* d_out, int out_size, void* d_ws, size_t ws_size,
                              hipStream_t stream) {
    const float* c = (const float*)d_in[0];
    const float* w = (const float*)d_in[1];
    float* out = (float*)d_out;
    char* ws = (char*)d_ws;

    double* rnorm = (double*)ws;                         // 512 KB
    size_t off = (size_t)P * N * 8;
    unsigned* gcnt = (unsigned*)(ws + off);
    unsigned* govf = gcnt + 1;
    unsigned* glist = (unsigned*)(ws + off + 128);       // 4 MB
    unsigned short* z2 = (unsigned short*)(ws + off + 128 + (size_t)CAP * 4);  // 32 MB
    size_t need = off + 128 + (size_t)CAP * 4 + (size_t)N * 4096 * 2;

    k_norms<<<(P * N + 255) / 256, 256, 0, stream>>>(c, w, rnorm);

    if (ws_size >= need) {
        k_init<<<1, 1, 0, stream>>>(gcnt, govf);
        k_prep2<<<N, 256, 0, stream>>>(c, w, rnorm, z2);
        k_gemm<4096, true><<<NBLK, 256, 0, stream>>>(z2, out, gcnt, govf, glist);
        k_fix2<<<256, 256, 0, stream>>>(c, w, rnorm, gcnt, glist, out);
        k_guard<<<2048, 256, 0, stream>>>(c, w, rnorm, govf, out);
    } else {
        unsigned short* zb = (unsigned short*)(ws + off);
        k_prep1<<<N, 256, 0, stream>>>(c, w, rnorm, zb);
        k_gemm<2048, false><<<NBLK, 256, 0, stream>>>(zb, out, nullptr, nullptr, nullptr);
        k_fix_full<<<(size_t)N * N / 1024, 256, 0, stream>>>(c, w, rnorm, out);
    }
}